// Round 2
// baseline (372.351 us; speedup 1.0000x reference)
//
#include <hip/hip_runtime.h>

#define DIM 128

typedef __attribute__((ext_vector_type(8))) short bf16x8;
typedef __attribute__((ext_vector_type(4))) float f32x4;

// ---- ws layout (float offsets) ----
#define WS_S      0                      // scalar S = sum(e)   (atomic)
#define WS_SUMEE  8                      // 128                 (atomic)
#define WS_C      136                    // 128  c = W_c2 @ sum_eE
#define WS_B12    264                    // 128  b_c1 + b_c2
#define WS_WBF    512                    // 32768 bf16 (=16384 floats): Wcat[n][k]
#define WS_GE     16896                  // 128  ge partial sums (atomic)
#define WS_Z2     17024                  // scalar Z = sum(exp(logit)) (atomic)
#define WS_SP     17152                  // N    sp_i
#define WS_E      (17152 + 262144)       // N    e_i
#define WS_WEXP   (17152 + 2 * 262144)   // N    exp(logit_i)
// total = 803,584 floats = 3.2 MB (< round-1's working 4.28 MB)

__device__ __forceinline__ unsigned short f2bf(float f) {
    union { float f; unsigned u; } v; v.f = f;
    unsigned r = v.u + 0x7fffu + ((v.u >> 16) & 1u);
    return (unsigned short)(r >> 16);
}

__device__ __forceinline__ float bfbits(unsigned u) {
    union { unsigned u; float f; } v; v.u = u;
    return v.f;
}

// ---------------- K1: init accumulators, convert weights to bf16, b12 ----------------
__global__ __launch_bounds__(256) void k1_init(const float* __restrict__ Wc1,
                                               const float* __restrict__ Wc2,
                                               const float* __restrict__ bc1,
                                               const float* __restrict__ bc2,
                                               float* __restrict__ ws) {
    int gid = blockIdx.x * 256 + threadIdx.x;
    unsigned short* wbf = (unsigned short*)(ws + WS_WBF);
    if (gid < 32768) {
        int n = gid >> 7, k = gid & 127;
        float v = (n < 128) ? Wc1[n * 128 + k] : Wc2[(n - 128) * 128 + k];
        wbf[gid] = f2bf(v);
    }
    if (gid < 128) {
        ws[WS_SUMEE + gid] = 0.f;
        ws[WS_GE + gid] = 0.f;
        ws[WS_B12 + gid] = bc1[gid] + bc2[gid];
    }
    if (gid == 0) { ws[WS_S] = 0.f; ws[WS_Z2] = 0.f; }
}

// ---------------- K2: one pass over E -> sp, e, S, sum_eE ----------------
__global__ __launch_bounds__(256) void k2_stats(const float* __restrict__ E,
                                                const float* __restrict__ v,
                                                const float* __restrict__ wpa,
                                                const float* __restrict__ bpa,
                                                float* __restrict__ ws) {
    __shared__ float red[16][128];
    __shared__ float redS[16];
    int t = threadIdx.x;
    int wave = t >> 6, lane = t & 63;
    int cl = lane & 15, rs = lane >> 4;
    int row0 = blockIdx.x * 128;
    const float4* E4 = (const float4*)E;

    float4 va = ((const float4*)v)[cl];
    float4 vb = ((const float4*)v)[16 + cl];
    float4 pa = ((const float4*)wpa)[cl];
    float4 pb = ((const float4*)wpa)[16 + cl];
    float bias = bpa[0];

    float4 acc0 = {0.f, 0.f, 0.f, 0.f}, acc1 = {0.f, 0.f, 0.f, 0.f};
    float se = 0.f;
    float* sp_ws = ws + WS_SP;
    float* e_ws = ws + WS_E;

#pragma unroll
    for (int it = 0; it < 8; ++it) {
        int row = row0 + it * 16 + wave * 4 + rs;
        float4 x0 = E4[row * 32 + cl];
        float4 x1 = E4[row * 32 + 16 + cl];
        float dv = x0.x * va.x + x0.y * va.y + x0.z * va.z + x0.w * va.w
                 + x1.x * vb.x + x1.y * vb.y + x1.z * vb.z + x1.w * vb.w;
        float dp = x0.x * pa.x + x0.y * pa.y + x0.z * pa.z + x0.w * pa.w
                 + x1.x * pb.x + x1.y * pb.y + x1.z * pb.z + x1.w * pb.w;
        for (int off = 1; off < 16; off <<= 1) {
            dv += __shfl_xor(dv, off);
            dp += __shfl_xor(dp, off);
        }
        float e = __expf(dp + bias);
        if (cl == 0) {
            sp_ws[row] = dv;
            e_ws[row] = e;
            se += e;
        }
        acc0.x += e * x0.x; acc0.y += e * x0.y; acc0.z += e * x0.z; acc0.w += e * x0.w;
        acc1.x += e * x1.x; acc1.y += e * x1.y; acc1.z += e * x1.z; acc1.w += e * x1.w;
    }
    int rr = wave * 4 + rs;
    float* dst = red[rr];
    dst[cl * 4 + 0] = acc0.x; dst[cl * 4 + 1] = acc0.y;
    dst[cl * 4 + 2] = acc0.z; dst[cl * 4 + 3] = acc0.w;
    dst[64 + cl * 4 + 0] = acc1.x; dst[64 + cl * 4 + 1] = acc1.y;
    dst[64 + cl * 4 + 2] = acc1.z; dst[64 + cl * 4 + 3] = acc1.w;
    if (cl == 0) redS[rr] = se;
    __syncthreads();
    if (t < 128) {
        float s = 0.f;
#pragma unroll
        for (int r = 0; r < 16; ++r) s += red[r][t];
        atomicAdd(&ws[WS_SUMEE + t], s);
    }
    if (t == 0) {
        float s = 0.f;
#pragma unroll
        for (int r = 0; r < 16; ++r) s += redS[r];
        atomicAdd(&ws[WS_S], s);
    }
}

// ---------------- K3: c = W_c2 @ sum_eE (tiny) ----------------
__global__ __launch_bounds__(128) void k3_c(const float* __restrict__ Wc2,
                                            float* __restrict__ ws) {
    int j = threadIdx.x;
    const float4* row = (const float4*)(Wc2 + j * 128);
    const float4* se = (const float4*)(ws + WS_SUMEE);
    float4 s4 = {0.f, 0.f, 0.f, 0.f};
#pragma unroll
    for (int k = 0; k < 32; ++k) {
        float4 a = row[k], b = se[k];
        s4.x += a.x * b.x; s4.y += a.y * b.y; s4.z += a.z * b.z; s4.w += a.w * b.w;
    }
    ws[WS_C + j] = s4.x + s4.y + s4.z + s4.w;
}

// ---------------- K4: MFMA GEMM + fused epilogue + ge partials ----------------
// 4096 blocks x 512 threads (8 waves); 64 rows/block.
// Wave w: output cols j in [w*16, w*16+16): acc[rt][0]=u1 (W_c1 rows of Wcat),
// acc[rt][1]=u2 (W_c2 rows, Wcat cols 128+j) — same j, two stacked weight halves.
// launch_bounds(512,4): 4 waves/SIMD -> 2 blocks/CU resident (round-1 was 1).
__global__ __launch_bounds__(512, 4) void k4_main(const float* __restrict__ E,
                                                  const float* __restrict__ wvc,
                                                  const float* __restrict__ bvc_p,
                                                  float* __restrict__ ws) {
    __shared__ unsigned short Elds[64 * 136];   // bf16, row stride 136 shorts (pad 8)
    __shared__ float pim[8][128];               // pi partials, then ge partials (after barrier)
    __shared__ float e_lds[64], dinv_lds[64];   // e_lds becomes wexp after combine

    int t = threadIdx.x;
    int w = t >> 6, lane = t & 63, cl = lane & 15, q = lane >> 4;
    int row0 = blockIdx.x * 64;
    const unsigned short* wbf = (const unsigned short*)(ws + WS_WBF);

    // per-thread column constants (global, L2-hot; no LDS needed)
    int j = w * 16 + cl;
    float cj = ws[WS_C + j];
    float b12j = ws[WS_B12 + j];
    float wvcj = wvc[j];
    float bvc = bvc_p[0];
    float sp_r = (t < 64) ? ws[WS_SP + row0 + t] : 0.f;

    // B fragments (registers)
    bf16x8 bfr[2][4];
#pragma unroll
    for (int c2 = 0; c2 < 2; ++c2) {
        int ct = w + c2 * 8;
#pragma unroll
        for (int kt = 0; kt < 4; ++kt)
            bfr[c2][kt] = *(const bf16x8*)(wbf + (ct * 16 + cl) * 128 + kt * 32 + q * 8);
    }

    // Stage E tile -> LDS (fp32 -> bf16 RNE)
    const float4* E4 = (const float4*)E + (size_t)row0 * 32;
#pragma unroll
    for (int i = 0; i < 4; ++i) {
        int idx = t + 512 * i;
        int row = idx >> 5, kq = idx & 31;
        float4 x = E4[idx];
        unsigned p0 = (unsigned)f2bf(x.x) | ((unsigned)f2bf(x.y) << 16);
        unsigned p1 = (unsigned)f2bf(x.z) | ((unsigned)f2bf(x.w) << 16);
        *(uint2*)&Elds[row * 136 + kq * 4] = make_uint2(p0, p1);
    }
    if (t < 64) {
        float Sv = ws[WS_S];
        float ev = ws[WS_E + row0 + t];
        e_lds[t] = ev;
        dinv_lds[t] = 1.0f / (Sv - ev);
    }
    __syncthreads();

    // GEMM
    f32x4 acc[4][2];
#pragma unroll
    for (int rt = 0; rt < 4; ++rt) {
        acc[rt][0] = (f32x4){0.f, 0.f, 0.f, 0.f};
        acc[rt][1] = (f32x4){0.f, 0.f, 0.f, 0.f};
    }
#pragma unroll
    for (int rt = 0; rt < 4; ++rt) {
        bf16x8 a[4];
#pragma unroll
        for (int kt = 0; kt < 4; ++kt)
            a[kt] = *(const bf16x8*)&Elds[(rt * 16 + cl) * 136 + kt * 32 + q * 8];
#pragma unroll
        for (int kt = 0; kt < 4; ++kt) {
            acc[rt][0] = __builtin_amdgcn_mfma_f32_16x16x32_bf16(a[kt], bfr[0][kt], acc[rt][0], 0, 0, 0);
            acc[rt][1] = __builtin_amdgcn_mfma_f32_16x16x32_bf16(a[kt], bfr[1][kt], acc[rt][1], 0, 0, 0);
        }
    }

    // Epilogue: h = u1 + b12 + (c - e*u2)*dinv; partial pi = wvc*relu(h), reduce over 16 cols
#pragma unroll
    for (int rt = 0; rt < 4; ++rt) {
#pragma unroll
        for (int reg = 0; reg < 4; ++reg) {
            int row_it = rt * 16 + q * 4 + reg;
            float er = e_lds[row_it];
            float dinv = dinv_lds[row_it];
            float h = acc[rt][0][reg] + b12j + (cj - er * acc[rt][1][reg]) * dinv;
            float p = wvcj * fmaxf(h, 0.f);
            p += __shfl_xor(p, 1);
            p += __shfl_xor(p, 2);
            p += __shfl_xor(p, 4);
            p += __shfl_xor(p, 8);
            if (cl == 0) pim[w][row_it] = p;
        }
    }
    __syncthreads();

    // Combine pi across waves (t<64 == wave 0), exp, block-Z (no extra barrier: all wave 0)
    if (t < 64) {
        float pi = 0.f;
#pragma unroll
        for (int wv = 0; wv < 8; ++wv) pi += pim[wv][t];
        float we = __expf(sp_r + bvc + pi);
        ws[WS_WEXP + row0 + t] = we;
        e_lds[t] = we;           // epilogue readers are past the barrier
        float z = we;
        for (int off = 1; off < 64; off <<= 1) z += __shfl_xor(z, off);
        if (t == 0) atomicAdd(&ws[WS_Z2], z);
    }
    __syncthreads();

    // ge partials from the bf16 tile already in LDS: ge[d] += sum_r wexp[r]*E[r][d]
    // thread: c=cl (8-col chunk), rq=q; rows w*8 + rq*2 + {0,1}; reduce over rq via shfl.
    int r0 = w * 8 + q * 2;
    float acc8[8] = {0.f, 0.f, 0.f, 0.f, 0.f, 0.f, 0.f, 0.f};
#pragma unroll
    for (int rr = 0; rr < 2; ++rr) {
        int r = r0 + rr;
        float wer = e_lds[r];
        uint4 u = *(const uint4*)&Elds[r * 136 + cl * 8];
        acc8[0] += wer * bfbits(u.x << 16);
        acc8[1] += wer * bfbits(u.x & 0xffff0000u);
        acc8[2] += wer * bfbits(u.y << 16);
        acc8[3] += wer * bfbits(u.y & 0xffff0000u);
        acc8[4] += wer * bfbits(u.z << 16);
        acc8[5] += wer * bfbits(u.z & 0xffff0000u);
        acc8[6] += wer * bfbits(u.w << 16);
        acc8[7] += wer * bfbits(u.w & 0xffff0000u);
    }
#pragma unroll
    for (int jj = 0; jj < 8; ++jj) {
        acc8[jj] += __shfl_xor(acc8[jj], 16);
        acc8[jj] += __shfl_xor(acc8[jj], 32);
    }
    if (lane < 16) {
        float4 g0 = {acc8[0], acc8[1], acc8[2], acc8[3]};
        float4 g1 = {acc8[4], acc8[5], acc8[6], acc8[7]};
        *(float4*)&pim[w][cl * 8] = g0;
        *(float4*)&pim[w][cl * 8 + 4] = g1;
    }
    __syncthreads();
    if (t < 128) {
        float tot = 0.f;
#pragma unroll
        for (int wv = 0; wv < 8; ++wv) tot += pim[wv][t];
        atomicAdd(&ws[WS_GE + t], tot);
    }
}

// ---------------- K5: normalize + write outputs ----------------
__global__ __launch_bounds__(256) void k5_final(const float* __restrict__ ws,
                                                float* __restrict__ out) {
    int t = threadIdx.x, blk = blockIdx.x;
    float invZ = 1.0f / ws[WS_Z2];
    int i = blk * 256 + t;
    out[128 + i] = ws[WS_WEXP + i] * invZ;
    if (blk == 0 && t < 128) out[t] = ws[WS_GE + t] * invZ;
}

extern "C" void kernel_launch(void* const* d_in, const int* in_sizes, int n_in,
                              void* d_out, int out_size, void* d_ws, size_t ws_size,
                              hipStream_t stream) {
    const float* E   = (const float*)d_in[0];
    const float* v   = (const float*)d_in[1];
    const float* Wc1 = (const float*)d_in[2];
    const float* bc1 = (const float*)d_in[3];
    const float* Wc2 = (const float*)d_in[4];
    const float* bc2 = (const float*)d_in[5];
    const float* wpa = (const float*)d_in[6];
    const float* bpa = (const float*)d_in[7];
    const float* wvc = (const float*)d_in[8];
    const float* bvc = (const float*)d_in[9];
    float* ws  = (float*)d_ws;
    float* out = (float*)d_out;

    k1_init<<<128, 256, 0, stream>>>(Wc1, Wc2, bc1, bc2, ws);
    k2_stats<<<2048, 256, 0, stream>>>(E, v, wpa, bpa, ws);
    k3_c<<<1, 128, 0, stream>>>(Wc2, ws);
    k4_main<<<4096, 512, 0, stream>>>(E, wvc, bvc, ws);
    k5_final<<<1024, 256, 0, stream>>>(ws, out);
}

// Round 3
// 274.758 us; speedup vs baseline: 1.3552x; 1.3552x over previous
//
#include <hip/hip_runtime.h>

#define DIM 128

typedef __attribute__((ext_vector_type(8))) short bf16x8;
typedef __attribute__((ext_vector_type(4))) float f32x4;

// ---- ws layout (float offsets) ----  total 939,520 floats = 3.76 MB
#define WS_B12    0        // 128
#define WS_C      128      // 128  c = W_c2 @ sum_eE
#define WS_SUMEE  256      // 128
#define WS_S      384      // 1
#define WS_ZB     416      // 64   Z buckets (atomic, 64-way)
#define WS_GEB    512      // 32*128 ge buckets (atomic, 32-way)
#define WS_WBF    4608     // 32768 bf16 (=16384 floats): Wcat[n][k]
#define WS_EEP    20992    // 128*1024 sum_eE partials, [d*1024 + blk]
#define WS_SEP    152064   // 1024 S partials
#define WS_SP     153088   // N
#define WS_E      415232   // N
#define WS_WEXP   677376   // N

__device__ __forceinline__ unsigned short f2bf(float f) {
    union { float f; unsigned u; } v; v.f = f;
    unsigned r = v.u + 0x7fffu + ((v.u >> 16) & 1u);
    return (unsigned short)(r >> 16);
}

__device__ __forceinline__ float bfbits(unsigned u) {
    union { unsigned u; float f; } v; v.u = u;
    return v.f;
}

// ---------------- K1: weights->bf16, b12, zero atomic buckets ----------------
__global__ __launch_bounds__(256) void k1_init(const float* __restrict__ Wc1,
                                               const float* __restrict__ Wc2,
                                               const float* __restrict__ bc1,
                                               const float* __restrict__ bc2,
                                               float* __restrict__ ws) {
    int gid = blockIdx.x * 256 + threadIdx.x;
    unsigned short* wbf = (unsigned short*)(ws + WS_WBF);
    if (gid < 32768) {
        int n = gid >> 7, k = gid & 127;
        float v = (n < 128) ? Wc1[n * 128 + k] : Wc2[(n - 128) * 128 + k];
        wbf[gid] = f2bf(v);
    }
    if (gid < 4096) ws[WS_GEB + gid] = 0.f;
    if (gid < 128) ws[WS_B12 + gid] = bc1[gid] + bc2[gid];
    if (gid < 64) ws[WS_ZB + gid] = 0.f;
}

// ---------------- K2: one pass over E -> sp, e, per-block {S, sum_eE} partials ----------------
// 1024 blocks x 256 threads; 256 rows/block; quarter-wave (16 lanes) per row. NO global atomics.
__global__ __launch_bounds__(256) void k2_stats(const float* __restrict__ E,
                                                const float* __restrict__ v,
                                                const float* __restrict__ wpa,
                                                const float* __restrict__ bpa,
                                                float* __restrict__ ws) {
    __shared__ float red[16][128];
    __shared__ float redS[16];
    int t = threadIdx.x;
    int wave = t >> 6, lane = t & 63;
    int cl = lane & 15, rs = lane >> 4;
    int row0 = blockIdx.x * 256;
    const float4* E4 = (const float4*)E;

    float4 va = ((const float4*)v)[cl];
    float4 vb = ((const float4*)v)[16 + cl];
    float4 pa = ((const float4*)wpa)[cl];
    float4 pb = ((const float4*)wpa)[16 + cl];
    float bias = bpa[0];

    float4 acc0 = {0.f, 0.f, 0.f, 0.f}, acc1 = {0.f, 0.f, 0.f, 0.f};
    float se = 0.f;
    float* sp_ws = ws + WS_SP;
    float* e_ws = ws + WS_E;

#pragma unroll 4
    for (int it = 0; it < 16; ++it) {
        int row = row0 + it * 16 + wave * 4 + rs;
        float4 x0 = E4[row * 32 + cl];
        float4 x1 = E4[row * 32 + 16 + cl];
        float dv = x0.x * va.x + x0.y * va.y + x0.z * va.z + x0.w * va.w
                 + x1.x * vb.x + x1.y * vb.y + x1.z * vb.z + x1.w * vb.w;
        float dp = x0.x * pa.x + x0.y * pa.y + x0.z * pa.z + x0.w * pa.w
                 + x1.x * pb.x + x1.y * pb.y + x1.z * pb.z + x1.w * pb.w;
        for (int off = 1; off < 16; off <<= 1) {
            dv += __shfl_xor(dv, off);
            dp += __shfl_xor(dp, off);
        }
        float e = __expf(dp + bias);
        if (cl == 0) {
            sp_ws[row] = dv;
            e_ws[row] = e;
            se += e;
        }
        acc0.x += e * x0.x; acc0.y += e * x0.y; acc0.z += e * x0.z; acc0.w += e * x0.w;
        acc1.x += e * x1.x; acc1.y += e * x1.y; acc1.z += e * x1.z; acc1.w += e * x1.w;
    }
    int rr = wave * 4 + rs;
    float* dst = red[rr];
    dst[cl * 4 + 0] = acc0.x; dst[cl * 4 + 1] = acc0.y;
    dst[cl * 4 + 2] = acc0.z; dst[cl * 4 + 3] = acc0.w;
    dst[64 + cl * 4 + 0] = acc1.x; dst[64 + cl * 4 + 1] = acc1.y;
    dst[64 + cl * 4 + 2] = acc1.z; dst[64 + cl * 4 + 3] = acc1.w;
    if (cl == 0) redS[rr] = se;
    __syncthreads();
    if (t < 128) {
        float s = 0.f;
#pragma unroll
        for (int r = 0; r < 16; ++r) s += red[r][t];
        ws[WS_EEP + t * 1024 + blockIdx.x] = s;   // unique slot, plain store
    }
    if (t == 0) {
        float s = 0.f;
#pragma unroll
        for (int r = 0; r < 16; ++r) s += redS[r];
        ws[WS_SEP + blockIdx.x] = s;
    }
}

// ---------------- K2b: reduce partials -> SUMEE[128], S ----------------
__global__ __launch_bounds__(256) void k2b_reduce(float* __restrict__ ws) {
    __shared__ float r4[4];
    int t = threadIdx.x, blk = blockIdx.x;
    const float* src = (blk < 128) ? (ws + WS_EEP + blk * 1024) : (ws + WS_SEP);
    float s = src[t] + src[t + 256] + src[t + 512] + src[t + 768];
    for (int off = 1; off < 64; off <<= 1) s += __shfl_xor(s, off);
    if ((t & 63) == 0) r4[t >> 6] = s;
    __syncthreads();
    if (t == 0) {
        float tot = r4[0] + r4[1] + r4[2] + r4[3];
        if (blk < 128) ws[WS_SUMEE + blk] = tot;
        else ws[WS_S] = tot;
    }
}

// ---------------- K3: c = W_c2 @ sum_eE (tiny) ----------------
__global__ __launch_bounds__(128) void k3_c(const float* __restrict__ Wc2,
                                            float* __restrict__ ws) {
    int j = threadIdx.x;
    const float4* row = (const float4*)(Wc2 + j * 128);
    const float4* se = (const float4*)(ws + WS_SUMEE);
    float4 s4 = {0.f, 0.f, 0.f, 0.f};
#pragma unroll
    for (int k = 0; k < 32; ++k) {
        float4 a = row[k], b = se[k];
        s4.x += a.x * b.x; s4.y += a.y * b.y; s4.z += a.z * b.z; s4.w += a.w * b.w;
    }
    ws[WS_C + j] = s4.x + s4.y + s4.z + s4.w;
}

// ---------------- K4: MFMA GEMM + fused epilogue ----------------
// 4096 blocks x 512 threads (8 waves); 64 rows/block. 3 barriers, all waves
// active in every phase. Bucketed atomics only (32-way ge, 64-way Z).
__global__ __launch_bounds__(512, 6) void k4_main(const float* __restrict__ E,
                                                  const float* __restrict__ wvc,
                                                  const float* __restrict__ bvc_p,
                                                  float* __restrict__ ws) {
    __shared__ unsigned short Elds[64 * 136];   // bf16, row stride 136 shorts
    __shared__ float pim[8][64];                // per-wave pi partials
    __shared__ float gep[8][128];               // per-wave ge partials
    __shared__ float e_lds[64], dinv_lds[64];
    __shared__ float zw[8];

    int t = threadIdx.x;
    int w = t >> 6, lane = t & 63, cl = lane & 15, q = lane >> 4;
    int row0 = blockIdx.x * 64;
    const unsigned short* wbf = (const unsigned short*)(ws + WS_WBF);

    // per-thread constants (L2/L3-hot)
    int j = w * 16 + cl;
    float cj = ws[WS_C + j];
    float b12j = ws[WS_B12 + j];
    float wvcj = wvc[j];
    float bvc = bvc_p[0];
    int r0 = w * 8 + q * 2;                      // this lane's 2 ge/wexp rows
    float sp0 = ws[WS_SP + row0 + r0];
    float sp1 = ws[WS_SP + row0 + r0 + 1];

    // B fragments (registers): cols j for W_c1 (ct=w) and W_c2 (ct=w+8)
    bf16x8 bfr[2][4];
#pragma unroll
    for (int c2 = 0; c2 < 2; ++c2) {
        int ct = w + c2 * 8;
#pragma unroll
        for (int kt = 0; kt < 4; ++kt)
            bfr[c2][kt] = *(const bf16x8*)(wbf + (ct * 16 + cl) * 128 + kt * 32 + q * 8);
    }

    // Stage E tile -> LDS (fp32 -> bf16 RNE)
    const float4* E4 = (const float4*)E + (size_t)row0 * 32;
#pragma unroll
    for (int i = 0; i < 4; ++i) {
        int idx = t + 512 * i;
        int row = idx >> 5, kq = idx & 31;
        float4 x = E4[idx];
        unsigned p0 = (unsigned)f2bf(x.x) | ((unsigned)f2bf(x.y) << 16);
        unsigned p1 = (unsigned)f2bf(x.z) | ((unsigned)f2bf(x.w) << 16);
        *(uint2*)&Elds[row * 136 + kq * 4] = make_uint2(p0, p1);
    }
    if (t < 64) {
        float Sv = ws[WS_S];
        float ev = ws[WS_E + row0 + t];
        e_lds[t] = ev;
        dinv_lds[t] = 1.0f / (Sv - ev);
    }
    __syncthreads();

    // GEMM: 32 MFMA per wave
    f32x4 acc[4][2];
#pragma unroll
    for (int rt = 0; rt < 4; ++rt) {
        acc[rt][0] = (f32x4){0.f, 0.f, 0.f, 0.f};
        acc[rt][1] = (f32x4){0.f, 0.f, 0.f, 0.f};
    }
#pragma unroll
    for (int rt = 0; rt < 4; ++rt) {
        bf16x8 a[4];
#pragma unroll
        for (int kt = 0; kt < 4; ++kt)
            a[kt] = *(const bf16x8*)&Elds[(rt * 16 + cl) * 136 + kt * 32 + q * 8];
#pragma unroll
        for (int kt = 0; kt < 4; ++kt) {
            acc[rt][0] = __builtin_amdgcn_mfma_f32_16x16x32_bf16(a[kt], bfr[0][kt], acc[rt][0], 0, 0, 0);
            acc[rt][1] = __builtin_amdgcn_mfma_f32_16x16x32_bf16(a[kt], bfr[1][kt], acc[rt][1], 0, 0, 0);
        }
    }

    // Epilogue: h = u1 + b12 + (c - e*u2)*dinv; reduce wvc*relu(h) over 16 cols
#pragma unroll
    for (int rt = 0; rt < 4; ++rt) {
#pragma unroll
        for (int reg = 0; reg < 4; ++reg) {
            int row_it = rt * 16 + q * 4 + reg;
            float er = e_lds[row_it];
            float dinv = dinv_lds[row_it];
            float h = acc[rt][0][reg] + b12j + (cj - er * acc[rt][1][reg]) * dinv;
            float p = wvcj * fmaxf(h, 0.f);
            p += __shfl_xor(p, 1);
            p += __shfl_xor(p, 2);
            p += __shfl_xor(p, 4);
            p += __shfl_xor(p, 8);
            if (cl == 0) pim[w][row_it] = p;
        }
    }
    __syncthreads();

    // All-wave phase: wexp for this lane's 2 rows (16-lane redundant, LDS broadcast)
    float pi0 = 0.f, pi1 = 0.f;
#pragma unroll
    for (int wv = 0; wv < 8; ++wv) {
        pi0 += pim[wv][r0];
        pi1 += pim[wv][r0 + 1];
    }
    float we0 = __expf(sp0 + bvc + pi0);
    float we1 = __expf(sp1 + bvc + pi1);
    if (cl == 0) {
        ws[WS_WEXP + row0 + r0] = we0;
        ws[WS_WEXP + row0 + r0 + 1] = we1;
    }
    // per-wave Z: sum 8 rows (reduce across q; cl-redundant)
    float z = we0 + we1;
    z += __shfl_xor(z, 16);
    z += __shfl_xor(z, 32);
    if (lane == 0) zw[w] = z;

    // ge partials from bf16 tile in LDS: lane handles cols [cl*8, cl*8+8), rows r0..r0+1
    float acc8[8] = {0.f, 0.f, 0.f, 0.f, 0.f, 0.f, 0.f, 0.f};
#pragma unroll
    for (int rr = 0; rr < 2; ++rr) {
        int r = r0 + rr;
        float wer = rr ? we1 : we0;
        uint4 u = *(const uint4*)&Elds[r * 136 + cl * 8];
        acc8[0] += wer * bfbits(u.x << 16);
        acc8[1] += wer * bfbits(u.x & 0xffff0000u);
        acc8[2] += wer * bfbits(u.y << 16);
        acc8[3] += wer * bfbits(u.y & 0xffff0000u);
        acc8[4] += wer * bfbits(u.z << 16);
        acc8[5] += wer * bfbits(u.z & 0xffff0000u);
        acc8[6] += wer * bfbits(u.w << 16);
        acc8[7] += wer * bfbits(u.w & 0xffff0000u);
    }
#pragma unroll
    for (int jj = 0; jj < 8; ++jj) {
        acc8[jj] += __shfl_xor(acc8[jj], 16);
        acc8[jj] += __shfl_xor(acc8[jj], 32);
    }
    if (lane < 16) {
        *(float4*)&gep[w][cl * 8] = (float4){acc8[0], acc8[1], acc8[2], acc8[3]};
        *(float4*)&gep[w][cl * 8 + 4] = (float4){acc8[4], acc8[5], acc8[6], acc8[7]};
    }
    __syncthreads();

    if (t < 128) {
        float tot = 0.f;
#pragma unroll
        for (int wv = 0; wv < 8; ++wv) tot += gep[wv][t];
        atomicAdd(&ws[WS_GEB + (blockIdx.x & 31) * 128 + t], tot);   // 128 adds/address
    }
    if (t == 128) {
        float zs = zw[0] + zw[1] + zw[2] + zw[3] + zw[4] + zw[5] + zw[6] + zw[7];
        atomicAdd(&ws[WS_ZB + (blockIdx.x & 63)], zs);               // 64 adds/address
    }
}

// ---------------- K5: normalize + write outputs ----------------
// blocks 0..1023: attention weights; block 1024: group embedding
__global__ __launch_bounds__(256) void k5_final(const float* __restrict__ ws,
                                                float* __restrict__ out) {
    int t = threadIdx.x, blk = blockIdx.x;
    float z = ws[WS_ZB + (t & 63)];
    for (int off = 1; off < 64; off <<= 1) z += __shfl_xor(z, off);
    float invZ = 1.0f / z;
    if (blk < 1024) {
        int i = blk * 256 + t;
        out[128 + i] = ws[WS_WEXP + i] * invZ;
    } else if (t < 128) {
        float s = 0.f;
#pragma unroll
        for (int b = 0; b < 32; ++b) s += ws[WS_GEB + b * 128 + t];
        out[t] = s * invZ;
    }
}

extern "C" void kernel_launch(void* const* d_in, const int* in_sizes, int n_in,
                              void* d_out, int out_size, void* d_ws, size_t ws_size,
                              hipStream_t stream) {
    const float* E   = (const float*)d_in[0];
    const float* v   = (const float*)d_in[1];
    const float* Wc1 = (const float*)d_in[2];
    const float* bc1 = (const float*)d_in[3];
    const float* Wc2 = (const float*)d_in[4];
    const float* bc2 = (const float*)d_in[5];
    const float* wpa = (const float*)d_in[6];
    const float* bpa = (const float*)d_in[7];
    const float* wvc = (const float*)d_in[8];
    const float* bvc = (const float*)d_in[9];
    float* ws  = (float*)d_ws;
    float* out = (float*)d_out;

    k1_init<<<128, 256, 0, stream>>>(Wc1, Wc2, bc1, bc2, ws);
    k2_stats<<<1024, 256, 0, stream>>>(E, v, wpa, bpa, ws);
    k2b_reduce<<<129, 256, 0, stream>>>(ws);
    k3_c<<<1, 128, 0, stream>>>(Wc2, ws);
    k4_main<<<4096, 512, 0, stream>>>(E, wvc, bvc, ws);
    k5_final<<<1025, 256, 0, stream>>>(ws, out);
}